// Round 4
// baseline (3528.390 us; speedup 1.0000x reference)
//
#include <hip/hip_runtime.h>

#define N_NODES 50000
#define N_EDGES 800000
#define SCAN_BLOCKS 196  // ceil(N_NODES/256)

// ---------------- degree count ----------------
__global__ __launch_bounds__(256) void k_count(const int* __restrict__ src,
                                               const int* __restrict__ dst,
                                               int* __restrict__ deg_out,
                                               int* __restrict__ deg_in) {
    int e = blockIdx.x * 256 + threadIdx.x;
    if (e < N_EDGES) {
        atomicAdd(&deg_out[src[e]], 1);
        atomicAdd(&deg_in[dst[e]], 1);
    }
}

// ---------------- norms ----------------
__global__ __launch_bounds__(256) void k_norm(const int* __restrict__ deg_out,
                                              const int* __restrict__ deg_in,
                                              float* __restrict__ norm_src,
                                              float* __restrict__ norm_dst) {
    int n = blockIdx.x * 256 + threadIdx.x;
    if (n < N_NODES) {
        int dO = deg_out[n]; if (dO < 1) dO = 1;
        int dI = deg_in[n];  if (dI < 1) dI = 1;
        norm_src[n] = rsqrtf((float)dO);
        norm_dst[n] = rsqrtf((float)dI);
    }
}

// ---------------- two-level scan of deg_in ----------------
__global__ __launch_bounds__(256) void k_scan1(const int* __restrict__ deg,
                                               int* __restrict__ partials) {
    __shared__ int sm[4];
    int i = blockIdx.x * 256 + threadIdx.x;
    int v = (i < N_NODES) ? deg[i] : 0;
#pragma unroll
    for (int off = 32; off > 0; off >>= 1) v += __shfl_down(v, off);
    int lane = threadIdx.x & 63, w = threadIdx.x >> 6;
    if (lane == 0) sm[w] = v;
    __syncthreads();
    if (threadIdx.x == 0)
        partials[blockIdx.x] = sm[0] + sm[1] + sm[2] + sm[3];
}

__global__ __launch_bounds__(256) void k_scan2(int* __restrict__ partials,
                                               int* __restrict__ row_start) {
    __shared__ int sm[256];
    int t = threadIdx.x;
    int v = (t < SCAN_BLOCKS) ? partials[t] : 0;
    sm[t] = v;
    __syncthreads();
#pragma unroll
    for (int off = 1; off < 256; off <<= 1) {
        int tv = (t >= off) ? sm[t - off] : 0;
        __syncthreads();
        sm[t] += tv;
        __syncthreads();
    }
    if (t < SCAN_BLOCKS) partials[t] = sm[t] - v;  // exclusive
    if (t == 0) row_start[N_NODES] = N_EDGES;
}

__global__ __launch_bounds__(256) void k_scan3(const int* __restrict__ deg,
                                               const int* __restrict__ partials,
                                               int* __restrict__ row_start,
                                               int* __restrict__ cursor) {
    __shared__ int sm[256];
    int t = threadIdx.x;
    int i = blockIdx.x * 256 + t;
    int v = (i < N_NODES) ? deg[i] : 0;
    sm[t] = v;
    __syncthreads();
#pragma unroll
    for (int off = 1; off < 256; off <<= 1) {
        int tv = (t >= off) ? sm[t - off] : 0;
        __syncthreads();
        sm[t] += tv;
        __syncthreads();
    }
    if (i < N_NODES) {
        int excl = sm[t] - v + partials[blockIdx.x];
        row_start[i] = excl;
        cursor[i] = excl;
    }
}

// ---------------- CSR fill ----------------
__global__ __launch_bounds__(256) void k_fill(const int* __restrict__ src,
                                              const int* __restrict__ dst,
                                              const float* __restrict__ norm_src,
                                              int* __restrict__ cursor,
                                              int* __restrict__ csr_src,
                                              float* __restrict__ csr_w) {
    int e = blockIdx.x * 256 + threadIdx.x;
    if (e < N_EDGES) {
        int d = dst[e], s = src[e];
        int pos = atomicAdd(&cursor[d], 1);
        csr_src[pos] = s;
        csr_w[pos] = norm_src[s];
    }
}

// ---------------- GEMM: G = X @ W, X is (N,128), W is (128,128) ----------------
// 64 rows/block, 256 threads: thread = (ty,tx), ty:16 rows-groups x tx:16 col-groups.
// Each thread: 4 rows x 8 cols. W staged in 32-k chunks (16 KB LDS -> high occupancy).
// X prefetched one 4-k step ahead in registers to cover HBM latency.
__global__ __launch_bounds__(256) void k_gemm(const float* __restrict__ X,
                                              const float* __restrict__ W,
                                              float* __restrict__ G) {
    __shared__ float Wl[32 * 128];  // 16 KB chunk
    const int tx = threadIdx.x & 15;
    const int ty = threadIdx.x >> 4;
    const int r0 = blockIdx.x * 64 + ty * 4;
    const int c0 = tx * 8;

    bool rv[4];
#pragma unroll
    for (int i = 0; i < 4; ++i) rv[i] = (r0 + i) < N_NODES;

    float acc[4][8] = {};
    float4 xa[4], xb[4];
#pragma unroll
    for (int i = 0; i < 4; ++i)
        xa[i] = rv[i] ? *(const float4*)(X + (size_t)(r0 + i) * 128)
                      : make_float4(0.f, 0.f, 0.f, 0.f);

#pragma unroll
    for (int kc = 0; kc < 4; ++kc) {
        __syncthreads();  // protect previous chunk's readers
#pragma unroll
        for (int it = 0; it < 4; ++it) {
            int idx = threadIdx.x * 4 + it * 1024;
            *(float4*)&Wl[idx] = *(const float4*)&W[kc * 4096 + idx];
        }
        __syncthreads();
#pragma unroll
        for (int ks = 0; ks < 32; ks += 4) {
            const int kg = kc * 32 + ks;
            if (kg + 4 < 128) {
#pragma unroll
                for (int i = 0; i < 4; ++i)
                    xb[i] = rv[i] ? *(const float4*)(X + (size_t)(r0 + i) * 128 + kg + 4)
                                  : make_float4(0.f, 0.f, 0.f, 0.f);
            }
#pragma unroll
            for (int kk = 0; kk < 4; ++kk) {
                float4 w0 = *(const float4*)&Wl[(ks + kk) * 128 + c0];
                float4 w1 = *(const float4*)&Wl[(ks + kk) * 128 + c0 + 4];
#pragma unroll
                for (int i = 0; i < 4; ++i) {
                    float a = (kk == 0) ? xa[i].x : (kk == 1) ? xa[i].y
                             : (kk == 2) ? xa[i].z : xa[i].w;
                    acc[i][0] = fmaf(a, w0.x, acc[i][0]);
                    acc[i][1] = fmaf(a, w0.y, acc[i][1]);
                    acc[i][2] = fmaf(a, w0.z, acc[i][2]);
                    acc[i][3] = fmaf(a, w0.w, acc[i][3]);
                    acc[i][4] = fmaf(a, w1.x, acc[i][4]);
                    acc[i][5] = fmaf(a, w1.y, acc[i][5]);
                    acc[i][6] = fmaf(a, w1.z, acc[i][6]);
                    acc[i][7] = fmaf(a, w1.w, acc[i][7]);
                }
            }
#pragma unroll
            for (int i = 0; i < 4; ++i) xa[i] = xb[i];
        }
    }
#pragma unroll
    for (int i = 0; i < 4; ++i) {
        if (rv[i]) {
            float* p = G + (size_t)(r0 + i) * 128 + c0;
            *(float4*)p = make_float4(acc[i][0], acc[i][1], acc[i][2], acc[i][3]);
            *(float4*)(p + 4) = make_float4(acc[i][4], acc[i][5], acc[i][6], acc[i][7]);
        }
    }
}

// ---------------- gather: Out[n] = act(norm_dst[n] * sum_e w_e * G[src_e] + b) ----------------
// One wave per node; lane covers features 2*lane, 2*lane+1. Edge loop unrolled x4 for MLP.
// PROJ: fuse final n_out = emb @ W_out + b_out into the layer-3 gather.
template <int ELU, int PROJ>
__global__ __launch_bounds__(256) void k_gather(const float* __restrict__ G,
                                                const int* __restrict__ row_start,
                                                const int* __restrict__ csr_src,
                                                const float* __restrict__ csr_w,
                                                const float* __restrict__ norm_dst,
                                                const float* __restrict__ bias,
                                                float* __restrict__ Out,
                                                const float* __restrict__ Wo,
                                                const float* __restrict__ bo,
                                                float* __restrict__ proj_out) {
    int n = (blockIdx.x * 256 + threadIdx.x) >> 6;
    int lane = threadIdx.x & 63;
    if (n >= N_NODES) return;
    int e0 = row_start[n], e1 = row_start[n + 1];
    float ax0 = 0.f, ay0 = 0.f, ax1 = 0.f, ay1 = 0.f;
    float ax2 = 0.f, ay2 = 0.f, ax3 = 0.f, ay3 = 0.f;
    int e = e0;
    for (; e + 4 <= e1; e += 4) {
        int s0 = csr_src[e], s1 = csr_src[e + 1], s2 = csr_src[e + 2], s3 = csr_src[e + 3];
        float w0 = csr_w[e], w1 = csr_w[e + 1], w2 = csr_w[e + 2], w3 = csr_w[e + 3];
        float2 g0 = *(const float2*)(G + (size_t)s0 * 128 + lane * 2);
        float2 g1 = *(const float2*)(G + (size_t)s1 * 128 + lane * 2);
        float2 g2 = *(const float2*)(G + (size_t)s2 * 128 + lane * 2);
        float2 g3 = *(const float2*)(G + (size_t)s3 * 128 + lane * 2);
        ax0 = fmaf(w0, g0.x, ax0); ay0 = fmaf(w0, g0.y, ay0);
        ax1 = fmaf(w1, g1.x, ax1); ay1 = fmaf(w1, g1.y, ay1);
        ax2 = fmaf(w2, g2.x, ax2); ay2 = fmaf(w2, g2.y, ay2);
        ax3 = fmaf(w3, g3.x, ax3); ay3 = fmaf(w3, g3.y, ay3);
    }
    for (; e < e1; ++e) {
        int s0 = csr_src[e];
        float w0 = csr_w[e];
        float2 g0 = *(const float2*)(G + (size_t)s0 * 128 + lane * 2);
        ax0 = fmaf(w0, g0.x, ax0); ay0 = fmaf(w0, g0.y, ay0);
    }
    float nd = norm_dst[n];
    float2 b = *(const float2*)(bias + lane * 2);
    float ox = fmaf(nd, (ax0 + ax1) + (ax2 + ax3), b.x);
    float oy = fmaf(nd, (ay0 + ay1) + (ay2 + ay3), b.y);
    if (ELU) {
        ox = ox > 0.f ? ox : expm1f(ox);
        oy = oy > 0.f ? oy : expm1f(oy);
    }
    *(float2*)(Out + (size_t)n * 128 + lane * 2) = make_float2(ox, oy);
    if (PROJ) {
        // lane covers k = 2*lane, 2*lane+1 of the 128-dim dot with W_out (128x2)
        float a0 = ox * Wo[lane * 4 + 0] + oy * Wo[lane * 4 + 2];
        float a1 = ox * Wo[lane * 4 + 1] + oy * Wo[lane * 4 + 3];
#pragma unroll
        for (int off = 32; off > 0; off >>= 1) {
            a0 += __shfl_down(a0, off);
            a1 += __shfl_down(a1, off);
        }
        if (lane == 0) {
            proj_out[n * 2 + 0] = a0 + bo[0];
            proj_out[n * 2 + 1] = a1 + bo[1];
        }
    }
}

extern "C" void kernel_launch(void* const* d_in, const int* in_sizes, int n_in,
                              void* d_out, int out_size, void* d_ws, size_t ws_size,
                              hipStream_t stream) {
    const float* x     = (const float*)d_in[0];
    const int*   src   = (const int*)d_in[1];
    const int*   dst   = (const int*)d_in[2];
    const float* W1    = (const float*)d_in[3];
    const float* b1    = (const float*)d_in[4];
    const float* W2    = (const float*)d_in[5];
    const float* b2    = (const float*)d_in[6];
    const float* W3    = (const float*)d_in[7];
    const float* b3    = (const float*)d_in[8];
    const float* W_out = (const float*)d_in[9];
    const float* b_out = (const float*)d_in[10];

    float* out = (float*)d_out;                 // n_out: N*2, then n_embed: N*128
    float* emb = out + (size_t)N_NODES * 2;

    char* ws = (char*)d_ws;
    const size_t P_N  = 200192;   // pad(N*4)
    const size_t P_E  = 3200000;  // E*4 (512-aligned)
    const size_t P_H  = 25600000; // N*128*4 (512-aligned)
    int*   deg_out  = (int*)(ws + 0);
    int*   deg_in   = (int*)(ws + P_N);
    float* norm_src = (float*)(ws + 2 * P_N);
    float* norm_dst = (float*)(ws + 3 * P_N);
    int*   row_start= (int*)(ws + 4 * P_N);
    int*   cursor   = (int*)(ws + 5 * P_N);
    // deg_out is dead after k_norm; reuse for scan partials (disjoint from cursor).
    int*   partials = deg_out;
    int*   csr_src  = (int*)(ws + 6 * P_N);
    float* csr_w    = (float*)(ws + 6 * P_N + P_E);
    float* bufA     = (float*)(ws + 6 * P_N + 2 * P_E);
    float* bufB     = (float*)(ws + 6 * P_N + 2 * P_E + P_H);

    const int gridE = (N_EDGES + 255) / 256;        // 3125
    const int gridN = (N_NODES + 255) / 256;        // 196
    const int gridG = (N_NODES + 63) / 64;          // 782 (gemm)
    const int gridW = (N_NODES * 64 + 255) / 256;   // 12500 (wave per node)

    hipMemsetAsync(deg_out, 0, 2 * P_N, stream);    // deg_out + deg_in
    k_count<<<gridE, 256, 0, stream>>>(src, dst, deg_out, deg_in);
    k_norm<<<gridN, 256, 0, stream>>>(deg_out, deg_in, norm_src, norm_dst);
    k_scan1<<<SCAN_BLOCKS, 256, 0, stream>>>(deg_in, partials);
    k_scan2<<<1, 256, 0, stream>>>(partials, row_start);
    k_scan3<<<SCAN_BLOCKS, 256, 0, stream>>>(deg_in, partials, row_start, cursor);
    k_fill<<<gridE, 256, 0, stream>>>(src, dst, norm_src, cursor, csr_src, csr_w);

    // layer 1: x -> bufA
    k_gemm<<<gridG, 256, 0, stream>>>(x, W1, bufB);
    k_gather<1, 0><<<gridW, 256, 0, stream>>>(bufB, row_start, csr_src, csr_w,
                                              norm_dst, b1, bufA, nullptr, nullptr, nullptr);
    // layer 2: bufA -> bufA
    k_gemm<<<gridG, 256, 0, stream>>>(bufA, W2, bufB);
    k_gather<1, 0><<<gridW, 256, 0, stream>>>(bufB, row_start, csr_src, csr_w,
                                              norm_dst, b2, bufA, nullptr, nullptr, nullptr);
    // layer 3: bufA -> emb (no activation), with fused projection -> out
    k_gemm<<<gridG, 256, 0, stream>>>(bufA, W3, bufB);
    k_gather<0, 1><<<gridW, 256, 0, stream>>>(bufB, row_start, csr_src, csr_w,
                                              norm_dst, b3, emb, W_out, b_out, out);
}

// Round 5
// 466.201 us; speedup vs baseline: 7.5684x; 7.5684x over previous
//
#include <hip/hip_runtime.h>

#define N_NODES 50000
#define N_EDGES 800000
#define SCAN_BLOCKS 196  // ceil(N_NODES/256)

// ---------------- degree count ----------------
__global__ __launch_bounds__(256) void k_count(const int* __restrict__ src,
                                               const int* __restrict__ dst,
                                               int* __restrict__ deg_out,
                                               int* __restrict__ deg_in) {
    int e = blockIdx.x * 256 + threadIdx.x;
    if (e < N_EDGES) {
        atomicAdd(&deg_out[src[e]], 1);
        atomicAdd(&deg_in[dst[e]], 1);
    }
}

// ---------------- norms ----------------
__global__ __launch_bounds__(256) void k_norm(const int* __restrict__ deg_out,
                                              const int* __restrict__ deg_in,
                                              float* __restrict__ norm_src,
                                              float* __restrict__ norm_dst) {
    int n = blockIdx.x * 256 + threadIdx.x;
    if (n < N_NODES) {
        int dO = deg_out[n]; if (dO < 1) dO = 1;
        int dI = deg_in[n];  if (dI < 1) dI = 1;
        norm_src[n] = rsqrtf((float)dO);
        norm_dst[n] = rsqrtf((float)dI);
    }
}

// ---------------- two-level scan of deg_in ----------------
__global__ __launch_bounds__(256) void k_scan1(const int* __restrict__ deg,
                                               int* __restrict__ partials) {
    __shared__ int sm[4];
    int i = blockIdx.x * 256 + threadIdx.x;
    int v = (i < N_NODES) ? deg[i] : 0;
#pragma unroll
    for (int off = 32; off > 0; off >>= 1) v += __shfl_down(v, off);
    int lane = threadIdx.x & 63, w = threadIdx.x >> 6;
    if (lane == 0) sm[w] = v;
    __syncthreads();
    if (threadIdx.x == 0)
        partials[blockIdx.x] = sm[0] + sm[1] + sm[2] + sm[3];
}

__global__ __launch_bounds__(256) void k_scan2(int* __restrict__ partials,
                                               int* __restrict__ row_start) {
    __shared__ int sm[256];
    int t = threadIdx.x;
    int v = (t < SCAN_BLOCKS) ? partials[t] : 0;
    sm[t] = v;
    __syncthreads();
#pragma unroll
    for (int off = 1; off < 256; off <<= 1) {
        int tv = (t >= off) ? sm[t - off] : 0;
        __syncthreads();
        sm[t] += tv;
        __syncthreads();
    }
    if (t < SCAN_BLOCKS) partials[t] = sm[t] - v;  // exclusive
    if (t == 0) row_start[N_NODES] = N_EDGES;
}

__global__ __launch_bounds__(256) void k_scan3(const int* __restrict__ deg,
                                               const int* __restrict__ partials,
                                               int* __restrict__ row_start,
                                               int* __restrict__ cursor) {
    __shared__ int sm[256];
    int t = threadIdx.x;
    int i = blockIdx.x * 256 + t;
    int v = (i < N_NODES) ? deg[i] : 0;
    sm[t] = v;
    __syncthreads();
#pragma unroll
    for (int off = 1; off < 256; off <<= 1) {
        int tv = (t >= off) ? sm[t - off] : 0;
        __syncthreads();
        sm[t] += tv;
        __syncthreads();
    }
    if (i < N_NODES) {
        int excl = sm[t] - v + partials[blockIdx.x];
        row_start[i] = excl;
        cursor[i] = excl;
    }
}

// ---------------- CSR fill ----------------
__global__ __launch_bounds__(256) void k_fill(const int* __restrict__ src,
                                              const int* __restrict__ dst,
                                              const float* __restrict__ norm_src,
                                              int* __restrict__ cursor,
                                              int* __restrict__ csr_src,
                                              float* __restrict__ csr_w) {
    int e = blockIdx.x * 256 + threadIdx.x;
    if (e < N_EDGES) {
        int d = dst[e], s = src[e];
        int pos = atomicAdd(&cursor[d], 1);
        csr_src[pos] = s;
        csr_w[pos] = norm_src[s];
    }
}

// ---------------- GEMM: G = X @ W, X is (N,128), W is (128,128) ----------------
// 64 rows/block, 256 threads. Thread (ty,tx): 4 rows x 8 cols (cols split c0 / c0+64,
// 2-way LDS aliasing = free). W staged in two 32 KB chunks -> 5 blocks/CU.
// No manual prefetch; occupancy hides HBM latency. (Round-4 lesson: full unroll +
// prefetch -> 256 VGPR + scratch spills -> 2.2 GB of HBM spill traffic.)
__global__ __launch_bounds__(256) void k_gemm(const float* __restrict__ X,
                                              const float* __restrict__ W,
                                              float* __restrict__ G) {
    __shared__ float Wl[64 * 128];  // 32 KB chunk
    const int tx = threadIdx.x & 15;
    const int ty = threadIdx.x >> 4;
    const int r0 = blockIdx.x * 64 + ty * 4;
    const int c0 = tx * 4;

    float acc[2][4][4] = {};
    for (int kc = 0; kc < 2; ++kc) {
        __syncthreads();  // protect previous chunk's readers
#pragma unroll
        for (int it = 0; it < 8; ++it) {
            int idx = threadIdx.x * 4 + it * 1024;
            *(float4*)&Wl[idx] = *(const float4*)&W[kc * 8192 + idx];
        }
        __syncthreads();
#pragma unroll 2
        for (int ks = 0; ks < 64; ks += 4) {
            float4 xa[4];
#pragma unroll
            for (int i = 0; i < 4; ++i) {
                int r = r0 + i;
                xa[i] = (r < N_NODES)
                          ? *(const float4*)(X + (size_t)r * 128 + kc * 64 + ks)
                          : make_float4(0.f, 0.f, 0.f, 0.f);
            }
#pragma unroll
            for (int kk = 0; kk < 4; ++kk) {
                float4 w0 = *(const float4*)&Wl[(ks + kk) * 128 + c0];
                float4 w1 = *(const float4*)&Wl[(ks + kk) * 128 + c0 + 64];
#pragma unroll
                for (int i = 0; i < 4; ++i) {
                    float a = (kk == 0) ? xa[i].x : (kk == 1) ? xa[i].y
                             : (kk == 2) ? xa[i].z : xa[i].w;
                    acc[0][i][0] = fmaf(a, w0.x, acc[0][i][0]);
                    acc[0][i][1] = fmaf(a, w0.y, acc[0][i][1]);
                    acc[0][i][2] = fmaf(a, w0.z, acc[0][i][2]);
                    acc[0][i][3] = fmaf(a, w0.w, acc[0][i][3]);
                    acc[1][i][0] = fmaf(a, w1.x, acc[1][i][0]);
                    acc[1][i][1] = fmaf(a, w1.y, acc[1][i][1]);
                    acc[1][i][2] = fmaf(a, w1.z, acc[1][i][2]);
                    acc[1][i][3] = fmaf(a, w1.w, acc[1][i][3]);
                }
            }
        }
    }
#pragma unroll
    for (int i = 0; i < 4; ++i) {
        int r = r0 + i;
        if (r < N_NODES) {
            float* p = G + (size_t)r * 128 + c0;
            *(float4*)p = make_float4(acc[0][i][0], acc[0][i][1], acc[0][i][2], acc[0][i][3]);
            *(float4*)(p + 64) = make_float4(acc[1][i][0], acc[1][i][1], acc[1][i][2], acc[1][i][3]);
        }
    }
}

// ---------------- gather: Out[n] = act(norm_dst[n] * sum_e w_e * G[src_e] + b) ----------------
// One wave per node; lane covers features 2*lane, 2*lane+1. Edge loop unrolled x4 for MLP.
// PROJ: fuse final n_out = emb @ W_out + b_out into the layer-3 gather.
template <int ELU, int PROJ>
__global__ __launch_bounds__(256) void k_gather(const float* __restrict__ G,
                                                const int* __restrict__ row_start,
                                                const int* __restrict__ csr_src,
                                                const float* __restrict__ csr_w,
                                                const float* __restrict__ norm_dst,
                                                const float* __restrict__ bias,
                                                float* __restrict__ Out,
                                                const float* __restrict__ Wo,
                                                const float* __restrict__ bo,
                                                float* __restrict__ proj_out) {
    int n = (blockIdx.x * 256 + threadIdx.x) >> 6;
    int lane = threadIdx.x & 63;
    if (n >= N_NODES) return;
    int e0 = row_start[n], e1 = row_start[n + 1];
    float ax0 = 0.f, ay0 = 0.f, ax1 = 0.f, ay1 = 0.f;
    float ax2 = 0.f, ay2 = 0.f, ax3 = 0.f, ay3 = 0.f;
    int e = e0;
    for (; e + 4 <= e1; e += 4) {
        int s0 = csr_src[e], s1 = csr_src[e + 1], s2 = csr_src[e + 2], s3 = csr_src[e + 3];
        float w0 = csr_w[e], w1 = csr_w[e + 1], w2 = csr_w[e + 2], w3 = csr_w[e + 3];
        float2 g0 = *(const float2*)(G + (size_t)s0 * 128 + lane * 2);
        float2 g1 = *(const float2*)(G + (size_t)s1 * 128 + lane * 2);
        float2 g2 = *(const float2*)(G + (size_t)s2 * 128 + lane * 2);
        float2 g3 = *(const float2*)(G + (size_t)s3 * 128 + lane * 2);
        ax0 = fmaf(w0, g0.x, ax0); ay0 = fmaf(w0, g0.y, ay0);
        ax1 = fmaf(w1, g1.x, ax1); ay1 = fmaf(w1, g1.y, ay1);
        ax2 = fmaf(w2, g2.x, ax2); ay2 = fmaf(w2, g2.y, ay2);
        ax3 = fmaf(w3, g3.x, ax3); ay3 = fmaf(w3, g3.y, ay3);
    }
    for (; e < e1; ++e) {
        int s0 = csr_src[e];
        float w0 = csr_w[e];
        float2 g0 = *(const float2*)(G + (size_t)s0 * 128 + lane * 2);
        ax0 = fmaf(w0, g0.x, ax0); ay0 = fmaf(w0, g0.y, ay0);
    }
    float nd = norm_dst[n];
    float2 b = *(const float2*)(bias + lane * 2);
    float ox = fmaf(nd, (ax0 + ax1) + (ax2 + ax3), b.x);
    float oy = fmaf(nd, (ay0 + ay1) + (ay2 + ay3), b.y);
    if (ELU) {
        ox = ox > 0.f ? ox : expm1f(ox);
        oy = oy > 0.f ? oy : expm1f(oy);
    }
    *(float2*)(Out + (size_t)n * 128 + lane * 2) = make_float2(ox, oy);
    if (PROJ) {
        // lane covers k = 2*lane, 2*lane+1 of the 128-dim dot with W_out (128x2)
        float a0 = ox * Wo[lane * 4 + 0] + oy * Wo[lane * 4 + 2];
        float a1 = ox * Wo[lane * 4 + 1] + oy * Wo[lane * 4 + 3];
#pragma unroll
        for (int off = 32; off > 0; off >>= 1) {
            a0 += __shfl_down(a0, off);
            a1 += __shfl_down(a1, off);
        }
        if (lane == 0) {
            proj_out[n * 2 + 0] = a0 + bo[0];
            proj_out[n * 2 + 1] = a1 + bo[1];
        }
    }
}

extern "C" void kernel_launch(void* const* d_in, const int* in_sizes, int n_in,
                              void* d_out, int out_size, void* d_ws, size_t ws_size,
                              hipStream_t stream) {
    const float* x     = (const float*)d_in[0];
    const int*   src   = (const int*)d_in[1];
    const int*   dst   = (const int*)d_in[2];
    const float* W1    = (const float*)d_in[3];
    const float* b1    = (const float*)d_in[4];
    const float* W2    = (const float*)d_in[5];
    const float* b2    = (const float*)d_in[6];
    const float* W3    = (const float*)d_in[7];
    const float* b3    = (const float*)d_in[8];
    const float* W_out = (const float*)d_in[9];
    const float* b_out = (const float*)d_in[10];

    float* out = (float*)d_out;                 // n_out: N*2, then n_embed: N*128
    float* emb = out + (size_t)N_NODES * 2;

    char* ws = (char*)d_ws;
    const size_t P_N  = 200192;   // pad(N*4)
    const size_t P_E  = 3200000;  // E*4 (512-aligned)
    const size_t P_H  = 25600000; // N*128*4 (512-aligned)
    int*   deg_out  = (int*)(ws + 0);
    int*   deg_in   = (int*)(ws + P_N);
    float* norm_src = (float*)(ws + 2 * P_N);
    float* norm_dst = (float*)(ws + 3 * P_N);
    int*   row_start= (int*)(ws + 4 * P_N);
    int*   cursor   = (int*)(ws + 5 * P_N);
    // deg_out is dead after k_norm; reuse for scan partials (disjoint from cursor).
    int*   partials = deg_out;
    int*   csr_src  = (int*)(ws + 6 * P_N);
    float* csr_w    = (float*)(ws + 6 * P_N + P_E);
    float* bufA     = (float*)(ws + 6 * P_N + 2 * P_E);
    float* bufB     = (float*)(ws + 6 * P_N + 2 * P_E + P_H);

    const int gridE = (N_EDGES + 255) / 256;        // 3125
    const int gridN = (N_NODES + 255) / 256;        // 196
    const int gridG = (N_NODES + 63) / 64;          // 782 (gemm)
    const int gridW = (N_NODES * 64 + 255) / 256;   // 12500 (wave per node)

    hipMemsetAsync(deg_out, 0, 2 * P_N, stream);    // deg_out + deg_in
    k_count<<<gridE, 256, 0, stream>>>(src, dst, deg_out, deg_in);
    k_norm<<<gridN, 256, 0, stream>>>(deg_out, deg_in, norm_src, norm_dst);
    k_scan1<<<SCAN_BLOCKS, 256, 0, stream>>>(deg_in, partials);
    k_scan2<<<1, 256, 0, stream>>>(partials, row_start);
    k_scan3<<<SCAN_BLOCKS, 256, 0, stream>>>(deg_in, partials, row_start, cursor);
    k_fill<<<gridE, 256, 0, stream>>>(src, dst, norm_src, cursor, csr_src, csr_w);

    // layer 1: x -> bufA
    k_gemm<<<gridG, 256, 0, stream>>>(x, W1, bufB);
    k_gather<1, 0><<<gridW, 256, 0, stream>>>(bufB, row_start, csr_src, csr_w,
                                              norm_dst, b1, bufA, nullptr, nullptr, nullptr);
    // layer 2: bufA -> bufA
    k_gemm<<<gridG, 256, 0, stream>>>(bufA, W2, bufB);
    k_gather<1, 0><<<gridW, 256, 0, stream>>>(bufB, row_start, csr_src, csr_w,
                                              norm_dst, b2, bufA, nullptr, nullptr, nullptr);
    // layer 3: bufA -> emb (no activation), with fused projection -> out
    k_gemm<<<gridG, 256, 0, stream>>>(bufA, W3, bufB);
    k_gather<0, 1><<<gridW, 256, 0, stream>>>(bufB, row_start, csr_src, csr_w,
                                              norm_dst, b3, emb, W_out, b_out, out);
}

// Round 6
// 422.325 us; speedup vs baseline: 8.3547x; 1.1039x over previous
//
#include <hip/hip_runtime.h>

#define N_NODES 50000
#define N_EDGES 800000
#define GRID_G 782        // ceil(N_NODES/64) gemm blocks
#define NB_HIST 64        // histogram blocks
#define EPB (N_EDGES / NB_HIST)   // 12500 edges per hist block
#define WORDS 25000       // N_NODES/2 packed 2x16 words
#define NORMB_BLOCKS 98   // ceil(WORDS/256); each covers 512 nodes

// ---------------- histogram degree count (no global atomics) ----------------
// Each block builds packed 2x16-bit histograms of its 12500-edge chunk in LDS,
// in 2 node-range passes per array (src -> partO, dst -> partI).
// Per-block per-pass increments <= 12500 < 65536 -> no carry into high half.
__global__ __launch_bounds__(256) void k_hist(const int* __restrict__ src,
                                              const int* __restrict__ dst,
                                              unsigned int* __restrict__ partO,
                                              unsigned int* __restrict__ partI) {
    __shared__ unsigned int h[12500];   // 50 KB: 25000 nodes packed 2 per word
    const int e0 = blockIdx.x * EPB;
    for (int kind = 0; kind < 2; ++kind) {
        const int* ids = kind ? dst : src;
        unsigned int* out = kind ? partI : partO;
        for (int p = 0; p < 2; ++p) {
            for (int i = threadIdx.x; i < 12500; i += 256) h[i] = 0;
            __syncthreads();
            const int base = p * 25000;
            for (int i = threadIdx.x; i < EPB; i += 256) {
                int id = ids[e0 + i] - base;
                if ((unsigned)id < 25000u)
                    atomicAdd(&h[id >> 1], (id & 1) ? 0x10000u : 1u);
            }
            __syncthreads();
            unsigned int* o = out + blockIdx.x * WORDS + p * 12500;
            for (int i = threadIdx.x; i < 12500; i += 256) o[i] = h[i];
            __syncthreads();
        }
    }
}

// ---------------- reduce partials -> degrees, norms, scan block-sums ----------------
// Thread w handles nodes 2w, 2w+1. Also emits per-block (512-node) deg_in sums
// for the scan (folds old k_norm + k_scan1).
__global__ __launch_bounds__(256) void k_normB(const unsigned int* __restrict__ partO,
                                               const unsigned int* __restrict__ partI,
                                               float* __restrict__ norm_src,
                                               float* __restrict__ norm_dst,
                                               int* __restrict__ deg_in,
                                               int* __restrict__ partials98) {
    __shared__ int sm4[4];
    int w = blockIdx.x * 256 + threadIdx.x;
    unsigned int lo_o = 0, hi_o = 0, lo_i = 0, hi_i = 0;
    if (w < WORDS) {
        for (int b = 0; b < NB_HIST; ++b) {
            unsigned int vo = partO[b * WORDS + w];
            unsigned int vi = partI[b * WORDS + w];
            lo_o += vo & 0xFFFFu; hi_o += vo >> 16;
            lo_i += vi & 0xFFFFu; hi_i += vi >> 16;
        }
        int n0 = 2 * w;
        *(float2*)&norm_src[n0] = make_float2(rsqrtf((float)max(lo_o, 1u)),
                                              rsqrtf((float)max(hi_o, 1u)));
        *(float2*)&norm_dst[n0] = make_float2(rsqrtf((float)max(lo_i, 1u)),
                                              rsqrtf((float)max(hi_i, 1u)));
        *(int2*)&deg_in[n0] = make_int2((int)lo_i, (int)hi_i);
    }
    int v = (int)(lo_i + hi_i);
#pragma unroll
    for (int off = 32; off > 0; off >>= 1) v += __shfl_down(v, off);
    int lane = threadIdx.x & 63, wv = threadIdx.x >> 6;
    if (lane == 0) sm4[wv] = v;
    __syncthreads();
    if (threadIdx.x == 0)
        partials98[blockIdx.x] = sm4[0] + sm4[1] + sm4[2] + sm4[3];
}

// ---------------- scan: exclusive prefix over deg_in (512 nodes/block) ----------------
// Carry over previous blocks computed inline from partials98 (wave 0 reduce).
__global__ __launch_bounds__(256) void k_scan(const int* __restrict__ deg_in,
                                              const int* __restrict__ partials98,
                                              int* __restrict__ row_start,
                                              int* __restrict__ cursor) {
    __shared__ int sm[256];
    __shared__ int carry_s;
    int t = threadIdx.x;
    if (t < 64) {
        int acc = 0;
        for (int i = t; i < blockIdx.x; i += 64) acc += partials98[i];
#pragma unroll
        for (int off = 32; off > 0; off >>= 1) acc += __shfl_down(acc, off);
        if (t == 0) carry_s = acc;
    }
    int n0 = blockIdx.x * 512 + t * 2;
    int a0 = 0, a1 = 0;
    if (n0 + 1 < N_NODES) {
        int2 d = *(const int2*)&deg_in[n0];
        a0 = d.x; a1 = d.y;
    } else if (n0 < N_NODES) {
        a0 = deg_in[n0];
    }
    sm[t] = a0 + a1;
    __syncthreads();
#pragma unroll
    for (int off = 1; off < 256; off <<= 1) {
        int tv = (t >= off) ? sm[t - off] : 0;
        __syncthreads();
        sm[t] += tv;
        __syncthreads();
    }
    int excl = sm[t] - (a0 + a1) + carry_s;
    if (n0 < N_NODES) { row_start[n0] = excl; cursor[n0] = excl; }
    if (n0 + 1 < N_NODES) { row_start[n0 + 1] = excl + a0; cursor[n0 + 1] = excl + a0; }
    if (blockIdx.x == 0 && t == 0) row_start[N_NODES] = N_EDGES;
}

// ---------------- GEMM body: G = X @ W (N,128)x(128,128) ----------------
// 64 rows/block; thread (ty,tx): 4 rows x 8 cols split c0/c0+64 (2-way LDS alias = free).
// W staged in two 32 KB chunks. No manual prefetch (round-4 spill lesson).
__device__ __forceinline__ void gemm_body(const float* __restrict__ X,
                                          const float* __restrict__ W,
                                          float* __restrict__ G,
                                          float* __restrict__ Wl, int bid) {
    const int tx = threadIdx.x & 15;
    const int ty = threadIdx.x >> 4;
    const int r0 = bid * 64 + ty * 4;
    const int c0 = tx * 4;

    float acc[2][4][4] = {};
    for (int kc = 0; kc < 2; ++kc) {
        __syncthreads();
#pragma unroll
        for (int it = 0; it < 8; ++it) {
            int idx = threadIdx.x * 4 + it * 1024;
            *(float4*)&Wl[idx] = *(const float4*)&W[kc * 8192 + idx];
        }
        __syncthreads();
#pragma unroll 2
        for (int ks = 0; ks < 64; ks += 4) {
            float4 xa[4];
#pragma unroll
            for (int i = 0; i < 4; ++i) {
                int r = r0 + i;
                xa[i] = (r < N_NODES)
                          ? *(const float4*)(X + (size_t)r * 128 + kc * 64 + ks)
                          : make_float4(0.f, 0.f, 0.f, 0.f);
            }
#pragma unroll
            for (int kk = 0; kk < 4; ++kk) {
                float4 w0 = *(const float4*)&Wl[(ks + kk) * 128 + c0];
                float4 w1 = *(const float4*)&Wl[(ks + kk) * 128 + c0 + 64];
#pragma unroll
                for (int i = 0; i < 4; ++i) {
                    float a = (kk == 0) ? xa[i].x : (kk == 1) ? xa[i].y
                             : (kk == 2) ? xa[i].z : xa[i].w;
                    acc[0][i][0] = fmaf(a, w0.x, acc[0][i][0]);
                    acc[0][i][1] = fmaf(a, w0.y, acc[0][i][1]);
                    acc[0][i][2] = fmaf(a, w0.z, acc[0][i][2]);
                    acc[0][i][3] = fmaf(a, w0.w, acc[0][i][3]);
                    acc[1][i][0] = fmaf(a, w1.x, acc[1][i][0]);
                    acc[1][i][1] = fmaf(a, w1.y, acc[1][i][1]);
                    acc[1][i][2] = fmaf(a, w1.z, acc[1][i][2]);
                    acc[1][i][3] = fmaf(a, w1.w, acc[1][i][3]);
                }
            }
        }
    }
#pragma unroll
    for (int i = 0; i < 4; ++i) {
        int r = r0 + i;
        if (r < N_NODES) {
            float* p = G + (size_t)r * 128 + c0;
            *(float4*)p = make_float4(acc[0][i][0], acc[0][i][1], acc[0][i][2], acc[0][i][3]);
            *(float4*)(p + 64) = make_float4(acc[1][i][0], acc[1][i][1], acc[1][i][2], acc[1][i][3]);
        }
    }
}

__global__ __launch_bounds__(256) void k_gemm(const float* __restrict__ X,
                                              const float* __restrict__ W,
                                              float* __restrict__ G) {
    __shared__ float Wl[64 * 128];
    gemm_body(X, W, G, Wl, blockIdx.x);
}

// ---------------- fused: GEMM1 (graph-independent) + CSR fill ----------------
__global__ __launch_bounds__(256) void k_gemm_fill(const float* __restrict__ X,
                                                   const float* __restrict__ W,
                                                   float* __restrict__ G,
                                                   const int* __restrict__ src,
                                                   const int* __restrict__ dst,
                                                   const float* __restrict__ norm_src,
                                                   int* __restrict__ cursor,
                                                   int2* __restrict__ csr) {
    __shared__ float Wl[64 * 128];
    if (blockIdx.x < GRID_G) {
        gemm_body(X, W, G, Wl, blockIdx.x);
    } else {
        int e = (blockIdx.x - GRID_G) * 256 + threadIdx.x;
        if (e < N_EDGES) {
            int d = dst[e], s = src[e];
            int pos = atomicAdd(&cursor[d], 1);
            csr[pos] = make_int2(s, __float_as_int(norm_src[s]));
        }
    }
}

// ---------------- gather: Out[n] = act(norm_dst[n] * sum_e w_e * G[src_e] + b) ----------------
template <int ELU, int PROJ>
__global__ __launch_bounds__(256) void k_gather(const float* __restrict__ G,
                                                const int* __restrict__ row_start,
                                                const int2* __restrict__ csr,
                                                const float* __restrict__ norm_dst,
                                                const float* __restrict__ bias,
                                                float* __restrict__ Out,
                                                const float* __restrict__ Wo,
                                                const float* __restrict__ bo,
                                                float* __restrict__ proj_out) {
    int n = (blockIdx.x * 256 + threadIdx.x) >> 6;
    int lane = threadIdx.x & 63;
    if (n >= N_NODES) return;
    int e0 = row_start[n], e1 = row_start[n + 1];
    float ax0 = 0.f, ay0 = 0.f, ax1 = 0.f, ay1 = 0.f;
    float ax2 = 0.f, ay2 = 0.f, ax3 = 0.f, ay3 = 0.f;
    int e = e0;
    for (; e + 4 <= e1; e += 4) {
        int2 c0 = csr[e], c1 = csr[e + 1], c2 = csr[e + 2], c3 = csr[e + 3];
        float2 g0 = *(const float2*)(G + (size_t)c0.x * 128 + lane * 2);
        float2 g1 = *(const float2*)(G + (size_t)c1.x * 128 + lane * 2);
        float2 g2 = *(const float2*)(G + (size_t)c2.x * 128 + lane * 2);
        float2 g3 = *(const float2*)(G + (size_t)c3.x * 128 + lane * 2);
        float w0 = __int_as_float(c0.y), w1 = __int_as_float(c1.y);
        float w2 = __int_as_float(c2.y), w3 = __int_as_float(c3.y);
        ax0 = fmaf(w0, g0.x, ax0); ay0 = fmaf(w0, g0.y, ay0);
        ax1 = fmaf(w1, g1.x, ax1); ay1 = fmaf(w1, g1.y, ay1);
        ax2 = fmaf(w2, g2.x, ax2); ay2 = fmaf(w2, g2.y, ay2);
        ax3 = fmaf(w3, g3.x, ax3); ay3 = fmaf(w3, g3.y, ay3);
    }
    for (; e < e1; ++e) {
        int2 c = csr[e];
        float w = __int_as_float(c.y);
        float2 g = *(const float2*)(G + (size_t)c.x * 128 + lane * 2);
        ax0 = fmaf(w, g.x, ax0); ay0 = fmaf(w, g.y, ay0);
    }
    float nd = norm_dst[n];
    float2 b = *(const float2*)(bias + lane * 2);
    float ox = fmaf(nd, (ax0 + ax1) + (ax2 + ax3), b.x);
    float oy = fmaf(nd, (ay0 + ay1) + (ay2 + ay3), b.y);
    if (ELU) {
        ox = ox > 0.f ? ox : expm1f(ox);
        oy = oy > 0.f ? oy : expm1f(oy);
    }
    *(float2*)(Out + (size_t)n * 128 + lane * 2) = make_float2(ox, oy);
    if (PROJ) {
        float a0 = ox * Wo[lane * 4 + 0] + oy * Wo[lane * 4 + 2];
        float a1 = ox * Wo[lane * 4 + 1] + oy * Wo[lane * 4 + 3];
#pragma unroll
        for (int off = 32; off > 0; off >>= 1) {
            a0 += __shfl_down(a0, off);
            a1 += __shfl_down(a1, off);
        }
        if (lane == 0) {
            proj_out[n * 2 + 0] = a0 + bo[0];
            proj_out[n * 2 + 1] = a1 + bo[1];
        }
    }
}

extern "C" void kernel_launch(void* const* d_in, const int* in_sizes, int n_in,
                              void* d_out, int out_size, void* d_ws, size_t ws_size,
                              hipStream_t stream) {
    const float* x     = (const float*)d_in[0];
    const int*   src   = (const int*)d_in[1];
    const int*   dst   = (const int*)d_in[2];
    const float* W1    = (const float*)d_in[3];
    const float* b1    = (const float*)d_in[4];
    const float* W2    = (const float*)d_in[5];
    const float* b2    = (const float*)d_in[6];
    const float* W3    = (const float*)d_in[7];
    const float* b3    = (const float*)d_in[8];
    const float* W_out = (const float*)d_in[9];
    const float* b_out = (const float*)d_in[10];

    float* out = (float*)d_out;                 // n_out: N*2, then n_embed: N*128
    float* emb = out + (size_t)N_NODES * 2;

    char* ws = (char*)d_ws;
    // layout (bytes):
    float* norm_src  = (float*)(ws + 0);             // 200192
    float* norm_dst  = (float*)(ws + 200192);        // 200192
    int*   deg_in    = (int*)(ws + 400384);          // 200192
    int*   row_start = (int*)(ws + 600576);          // 200704 (N+1 ints)
    int*   cursor    = (int*)(ws + 801280);          // 200192
    int*   partials98= (int*)(ws + 1001472);         // 512
    int2*  csr       = (int2*)(ws + 1001984);        // 6,400,000
    float* bufA      = (float*)(ws + 7401984);       // 25,600,000
    float* bufB      = (float*)(ws + 33001984);      // 25,600,000  (end 58.6 MB)
    // partO/partI (6.4 MB each) alias bufA: dead before gather1 writes bufA.
    unsigned int* partO = (unsigned int*)bufA;
    unsigned int* partI = partO + (size_t)NB_HIST * WORDS;

    const int gridW = (N_NODES * 64 + 255) / 256;   // 12500 (wave per node)
    const int gridF = GRID_G + (N_EDGES + 255) / 256;  // gemm + fill blocks

    k_hist<<<NB_HIST, 256, 0, stream>>>(src, dst, partO, partI);
    k_normB<<<NORMB_BLOCKS, 256, 0, stream>>>(partO, partI, norm_src, norm_dst,
                                              deg_in, partials98);
    k_scan<<<NORMB_BLOCKS, 256, 0, stream>>>(deg_in, partials98, row_start, cursor);
    // GEMM1 (x@W1, graph-independent) fused with CSR fill
    k_gemm_fill<<<gridF, 256, 0, stream>>>(x, W1, bufB, src, dst, norm_src,
                                           cursor, csr);
    k_gather<1, 0><<<gridW, 256, 0, stream>>>(bufB, row_start, csr, norm_dst, b1,
                                              bufA, nullptr, nullptr, nullptr);
    k_gemm<<<GRID_G, 256, 0, stream>>>(bufA, W2, bufB);
    k_gather<1, 0><<<gridW, 256, 0, stream>>>(bufB, row_start, csr, norm_dst, b2,
                                              bufA, nullptr, nullptr, nullptr);
    k_gemm<<<GRID_G, 256, 0, stream>>>(bufA, W3, bufB);
    k_gather<0, 1><<<gridW, 256, 0, stream>>>(bufB, row_start, csr, norm_dst, b3,
                                              emb, W_out, b_out, out);
}